// Round 15
// baseline (2046.034 us; speedup 1.0000x reference)
//
#include <hip/hip_runtime.h>
#include <hip/hip_bf16.h>

typedef __bf16 bf16x8 __attribute__((ext_vector_type(8)));
typedef float f32x4 __attribute__((ext_vector_type(4)));
typedef int   i32x4 __attribute__((ext_vector_type(4)));
typedef unsigned int u32x4 __attribute__((ext_vector_type(4)));
typedef unsigned short u16;
typedef unsigned int u32;
typedef unsigned char u8;

// ---------- helpers ----------
__device__ __forceinline__ u16 f2bf(float f) {
  union { float f; unsigned int i; } c;
  c.f = f;
  unsigned int x = c.i;
  return (u16)((x + 0x7fffu + ((x >> 16) & 1u)) >> 16);  // RNE
}
__device__ __forceinline__ float sigm(float x) { return 1.f / (1.f + __expf(-x)); }
__device__ __forceinline__ float tanh_fast(float x) {
  float e2 = __expf(2.f * x);
  return 1.f - 2.f / (e2 + 1.f);
}

// ---------- fp32 -> bf16 (vectorized; for w_ih) ----------
__global__ void cvt_f32_bf16_v4(const float* __restrict__ in, u16* __restrict__ out, int n4) {
  int stride = gridDim.x * blockDim.x;
  for (int i = blockIdx.x * blockDim.x + threadIdx.x; i < n4; i += stride) {
    float4 v = reinterpret_cast<const float4*>(in)[i];
    union { u16 u[4]; uint2 d; } o;
    o.u[0] = f2bf(v.x); o.u[1] = f2bf(v.y); o.u[2] = f2bf(v.z); o.u[3] = f2bf(v.w);
    reinterpret_cast<uint2*>(out)[i] = o.d;
  }
}

// ---------- x transpose + init 8 group h rings ----------
// h ring: [8 grp][2 buf][8 rows][1024 units] i8; tag = LSB of byte0 of each u32 word.
// buf0 first polled at s=2 (par 1) -> init words 0; buf1 at s=1 (par 0) -> init words 1.
__global__ void cvt_x_transpose(const float* __restrict__ in, u16* __restrict__ out,
                                u32* __restrict__ hring_u) {
  int gid = blockIdx.x * blockDim.x + threadIdx.x;
  if (gid < 32768) hring_u[gid] = ((gid >> 11) & 1) ? 1u : 0u;   // [grp3][buf1][2048 words]
  if (gid >= 64 * 512 * 64) return;
  int k8 = gid & 63, t = (gid >> 6) & 511, n = gid >> 15;
  const float* src = in + ((size_t)(n * 512 + t) << 9) + (k8 << 3);
  float4 a = reinterpret_cast<const float4*>(src)[0];
  float4 b = reinterpret_cast<const float4*>(src)[1];
  union { u16 u[8]; uint4 d; } o;
  o.u[0] = f2bf(a.x); o.u[1] = f2bf(a.y); o.u[2] = f2bf(a.z); o.u[3] = f2bf(a.w);
  o.u[4] = f2bf(b.x); o.u[5] = f2bf(b.y); o.u[6] = f2bf(b.z); o.u[7] = f2bf(b.w);
  *reinterpret_cast<uint4*>(out + ((size_t)(t * 64 + n) << 9) + (k8 << 3)) = o.d;
}

// ---------- XCD-local LSTM: 8 groups x 8 batch rows, 32 blocks/group, 1 block/CU ----------
// grp = blk&7 (round-robin -> one XCD per group; perf heuristic only). Block owns 32 units
// (128 gate-cols). w_hh int8 + per-col scale in LDS (128 KB). x-GEMM bf16 (wib from L2),
// h-GEMM int8 (exact i32 accum). 4 waves K-split; f32 gp (dequant fused). h exchanged as
// int8 + parity tags; polls sc0-first, escalate sc0+sc1 (correct on any dispatch).
__global__ void __launch_bounds__(256, 1) lstm_seq(
    const u16* __restrict__ xb,     // [512][64][512] bf16
    const u16* __restrict__ wib,    // [4096][512] bf16
    const float* __restrict__ w_hh, // [4096][1024] f32
    u8* __restrict__ hring,         // [8][2][8][1024] i8 (tagged)
    float* __restrict__ hTf,        // [64][1024] f32
    const float* __restrict__ b_ih, const float* __restrict__ b_hh) {
  __shared__ u8 wh[128][1056];      // 135,168 B; row = gate-col (gate*32+ul), 1056 pad
  __shared__ float gp[4][8][132];   // 16,896 B [wave][row][gatecol]
  __shared__ float invs[128];       // dequant scale per gate-col
  __shared__ float rmax[128][2];
  __shared__ u8 hstg8[8][32];       // h int8 staging

  int blk = blockIdx.x, t = threadIdx.x;
  int grp = blk & 7, sli = blk >> 3;
  int u0 = sli << 5;                // 32 units

  // ---- stage w_hh slice as int8 with per-row scale (once) ----
  {
    int l = t >> 1, hf = t & 1;     // row l = gate-col, half hf (512 cols)
    int gr = ((l >> 5) << 10) + u0 + (l & 31);
    const float* src = w_hh + ((size_t)gr << 10) + (hf << 9);
    float mx = 0.f;
    for (int c = 0; c < 128; ++c) {
      float4 v = reinterpret_cast<const float4*>(src)[c];
      mx = fmaxf(mx, fmaxf(fmaxf(fabsf(v.x), fabsf(v.y)), fmaxf(fabsf(v.z), fabsf(v.w))));
    }
    rmax[l][hf] = mx;
    __syncthreads();
    float m = fmaxf(rmax[l][0], rmax[l][1]);
    float q = m > 0.f ? 127.f / m : 0.f;
    if (hf == 0) invs[l] = m / (127.f * 127.f);
    for (int c = 0; c < 128; ++c) {
      float4 v = reinterpret_cast<const float4*>(src)[c];
      u32 b0 = (u32)(u8)(char)__float2int_rn(v.x * q);
      u32 b1 = (u32)(u8)(char)__float2int_rn(v.y * q);
      u32 b2 = (u32)(u8)(char)__float2int_rn(v.z * q);
      u32 b3 = (u32)(u8)(char)__float2int_rn(v.w * q);
      *(u32*)&wh[l][(hf << 9) + (c << 2)] = b0 | (b1 << 8) | (b2 << 16) | (b3 << 24);
    }
  }

  int lane = t & 63, wv = t >> 6;
  int lr = lane & 15, hi = lane >> 4, row8 = lane & 7;

  int pr = t >> 5, pu = t & 31;     // pointwise: row pr, unit pu (8x32 = 256 threads)
  float bI = b_ih[u0 + pu]        + b_hh[u0 + pu];
  float bF = b_ih[1024 + u0 + pu] + b_hh[1024 + u0 + pu];
  float bG = b_ih[2048 + u0 + pu] + b_hh[2048 + u0 + pu];
  float bO = b_ih[3072 + u0 + pu] + b_hh[3072 + u0 + pu];
  float c_ = 0.f;

  u8* hring_g = hring + (grp << 14);   // 2 bufs x 8KB
  __syncthreads();                      // weights staged

  for (int s = 0; s < 512; ++s) {
    f32x4 accf[8] = {};   // x-part (bf16 MFMA, f32)
    i32x4 acci[8] = {};   // h-part (i8 MFMA, exact i32)

    // x-GEMM: M=8 (rows dup), N=128, K=512 split 4 waves (K=128 each)
    {
      const u16* xrow = xb + ((size_t)s << 15) + (((grp << 3) + row8) << 9) + (wv << 7) + (hi << 3);
#pragma unroll
      for (int ks = 0; ks < 4; ++ks) {
        bf16x8 a = *(const bf16x8*)(xrow + ks * 32);
#pragma unroll
        for (int nt = 0; nt < 8; ++nt) {
          int col = (nt << 4) + lr;
          int grow = ((col >> 5) << 10) + u0 + (col & 31);
          bf16x8 bfr = *(const bf16x8*)(wib + ((size_t)grow << 9) + (wv << 7) + (ks << 5) + (hi << 3));
          accf[nt] = __builtin_amdgcn_mfma_f32_16x16x32_bf16(a, bfr, accf[nt], 0, 0, 0);
        }
      }
    }

    if (s > 0) {
      // poll-load h(s) K-slice: lane -> row row8, bytes (wv<<8)+(hi<<4), chunks +0/64/128/192
      const u8* hb = hring_g + ((s & 1) << 13) + (row8 << 10) + (wv << 8) + (hi << 4);
      u32 par = (u32)((s >> 1) & 1);
      u32x4 ha[4];
      int tries = 0;
      while (true) {
        if (tries < 6) {
          asm volatile(
            "global_load_dwordx4 %0, %4, off offset:0 sc0\n\t"
            "global_load_dwordx4 %1, %4, off offset:64 sc0\n\t"
            "global_load_dwordx4 %2, %4, off offset:128 sc0\n\t"
            "global_load_dwordx4 %3, %4, off offset:192 sc0"
            : "=v"(ha[0]), "=v"(ha[1]), "=v"(ha[2]), "=v"(ha[3])
            : "v"(hb) : "memory");
        } else {
          asm volatile(
            "global_load_dwordx4 %0, %4, off offset:0 sc0 sc1\n\t"
            "global_load_dwordx4 %1, %4, off offset:64 sc0 sc1\n\t"
            "global_load_dwordx4 %2, %4, off offset:128 sc0 sc1\n\t"
            "global_load_dwordx4 %3, %4, off offset:192 sc0 sc1"
            : "=v"(ha[0]), "=v"(ha[1]), "=v"(ha[2]), "=v"(ha[3])
            : "v"(hb) : "memory");
        }
        asm volatile("s_waitcnt vmcnt(0)" ::: "memory");
        __builtin_amdgcn_sched_barrier(0);          // rule #18
        u32 ok;
        if (par) {
          u32 r = 0xFFFFFFFFu;
#pragma unroll
          for (int i2 = 0; i2 < 4; ++i2)
            r &= (ha[i2][0] & ha[i2][1]) & (ha[i2][2] & ha[i2][3]);
          ok = r & 1u;
        } else {
          u32 r = 0u;
#pragma unroll
          for (int i2 = 0; i2 < 4; ++i2)
            r |= (ha[i2][0] | ha[i2][1]) | (ha[i2][2] | ha[i2][3]);
          ok = (~r) & 1u;
        }
        if (__all((int)ok)) break;
        if (++tries > (1 << 20)) break;             // fail loud, never hang
        if (tries > 6) __builtin_amdgcn_s_sleep(1);
      }
      __builtin_amdgcn_sched_barrier(0);
      // h-GEMM int8: K=256 per wave (4 k-steps of 64)
#pragma unroll
      for (int kk = 0; kk < 4; ++kk) {
        union { u32x4 u; i32x4 v; } av; av.u = ha[kk];
#pragma unroll
        for (int nt = 0; nt < 8; ++nt) {
          i32x4 bv = *(const i32x4*)&wh[(nt << 4) + lr][(wv << 8) + (kk << 6) + (hi << 4)];
          acci[nt] = __builtin_amdgcn_mfma_i32_16x16x64_i8(av.v, bv, acci[nt], 0, 0, 0);
        }
      }
    }

    // fused dequant + K-partial write (rows 0-7 real)
    if (hi < 2) {
#pragma unroll
      for (int nt = 0; nt < 8; ++nt) {
        float iv = invs[(nt << 4) + lr];
#pragma unroll
        for (int q = 0; q < 4; ++q)
          gp[wv][(hi << 2) + q][(nt << 4) + lr] = accf[nt][q] + (float)acci[nt][q] * iv;
      }
    }
    __syncthreads();

    // pointwise: reduce 4 wave-partials, cell update
    {
      float g0 = gp[0][pr][pu]      + gp[1][pr][pu]      + gp[2][pr][pu]      + gp[3][pr][pu]      + bI;
      float g1 = gp[0][pr][32 + pu] + gp[1][pr][32 + pu] + gp[2][pr][32 + pu] + gp[3][pr][32 + pu] + bF;
      float g2 = gp[0][pr][64 + pu] + gp[1][pr][64 + pu] + gp[2][pr][64 + pu] + gp[3][pr][64 + pu] + bG;
      float g3 = gp[0][pr][96 + pu] + gp[1][pr][96 + pu] + gp[2][pr][96 + pu] + gp[3][pr][96 + pu] + bO;
      float ii = sigm(g0), ff = sigm(g1), tg = tanh_fast(g2), oo = sigm(g3);
      float cn = ff * c_ + ii * tg;
      c_ = cn;
      float hv = oo * tanh_fast(cn);
      if (s == 511) {
        hTf[(((size_t)(grp << 3) + pr) << 10) + u0 + pu] = hv;   // plain; kernel-end flush
      } else {
        hstg8[pr][pu] = (u8)(char)__float2int_rn(hv * 127.f);
      }
    }
    __syncthreads();   // protects gp for next step AND publishes hstg8

    // tag + coherent store (64 threads, one u32 each; tags carry correctness)
    if (s < 511 && t < 64) {
      int r = t >> 3, j = t & 7;
      u32 w = *(const u32*)&hstg8[r][j << 2];
      w = (w & ~1u) | (u32)(((s + 1) >> 1) & 1);
      u8* dst = hring_g + (((s + 1) & 1) << 13) + (r << 10) + u0 + (j << 2);
      asm volatile("global_store_dword %0, %1, off sc0 sc1" :: "v"(dst), "v"(w) : "memory");
    }
  }
}

// ---------- FC head: block n computes out[n] ----------
__global__ void fc_head(const float* __restrict__ hTf, const float* __restrict__ fc_w,
                        const float* __restrict__ fc_b, float* __restrict__ out) {
  __shared__ float red[4];
  int n = blockIdx.x, t = threadIdx.x;
  float4 hv = *(const float4*)(hTf + (n << 10) + t * 4);
  float4 wv = *(const float4*)(fc_w + t * 4);
  float s = hv.x * wv.x + hv.y * wv.y + hv.z * wv.z + hv.w * wv.w;
#pragma unroll
  for (int o = 32; o; o >>= 1) s += __shfl_down(s, o, 64);
  if ((t & 63) == 0) red[t >> 6] = s;
  __syncthreads();
  if (t == 0) out[n] = sigm(red[0] + red[1] + red[2] + red[3] + fc_b[0]);
}

// ---------- launch ----------
extern "C" void kernel_launch(void* const* d_in, const int* in_sizes, int n_in,
                              void* d_out, int out_size, void* d_ws, size_t ws_size,
                              hipStream_t stream) {
  const float* x    = (const float*)d_in[0];
  const float* w_ih = (const float*)d_in[1];
  const float* w_hh = (const float*)d_in[2];
  const float* b_ih = (const float*)d_in[3];
  const float* b_hh = (const float*)d_in[4];
  const float* fc_w = (const float*)d_in[5];
  const float* fc_b = (const float*)d_in[6];
  float* out = (float*)d_out;

  char* ws = (char*)d_ws;
  u16*   xb    = (u16*)(ws);                   // 33,554,432 B
  u16*   wib   = (u16*)(ws + 33554432);        //  4,194,304 B
  u8*    hring = (u8*)(ws + 37748736);         //    131,072 B  [8][2][8][1024] i8
  float* hTf   = (float*)(ws + 37879808);      //    262,144 B

  cvt_x_transpose<<<8192, 256, 0, stream>>>(x, xb, (u32*)hring);
  cvt_f32_bf16_v4<<<512, 256, 0, stream>>>(w_ih, wib, 2097152 / 4);
  lstm_seq<<<256, 256, 0, stream>>>(xb, wib, w_hh, hring, hTf, b_ih, b_hh);
  fc_head<<<64, 256, 0, stream>>>(hTf, fc_w, fc_b, out);
}

// Round 16
// 1526.892 us; speedup vs baseline: 1.3400x; 1.3400x over previous
//
#include <hip/hip_runtime.h>
#include <hip/hip_bf16.h>

typedef __bf16 bf16x8 __attribute__((ext_vector_type(8)));
typedef float f32x4 __attribute__((ext_vector_type(4)));
typedef unsigned int u32x4 __attribute__((ext_vector_type(4)));
typedef unsigned short u16;
typedef unsigned int u32;

// ---------- helpers ----------
__device__ __forceinline__ u16 f2bf(float f) {
  union { float f; unsigned int i; } c;
  c.f = f;
  unsigned int x = c.i;
  return (u16)((x + 0x7fffu + ((x >> 16) & 1u)) >> 16);  // RNE
}
__device__ __forceinline__ float sigm(float x) { return 1.f / (1.f + __expf(-x)); }
__device__ __forceinline__ float tanh_fast(float x) {
  float e2 = __expf(2.f * x);
  return 1.f - 2.f / (e2 + 1.f);
}

// ---------- fp32 -> bf16 (vectorized; for w_ih) ----------
__global__ void cvt_f32_bf16_v4(const float* __restrict__ in, u16* __restrict__ out, int n4) {
  int stride = gridDim.x * blockDim.x;
  for (int i = blockIdx.x * blockDim.x + threadIdx.x; i < n4; i += stride) {
    float4 v = reinterpret_cast<const float4*>(in)[i];
    union { u16 u[4]; uint2 d; } o;
    o.u[0] = f2bf(v.x); o.u[1] = f2bf(v.y); o.u[2] = f2bf(v.z); o.u[3] = f2bf(v.w);
    reinterpret_cast<uint2*>(out)[i] = o.d;
  }
}

// ---------- x: [N=64][T=512][d=512] f32 -> [T][N][d] bf16 ; init 4 group h rings ----------
// Per group: [2][16 rows][512 u32words] (u32 = 2 bf16 units, low-elem LSB = parity tag).
// buf0 first polled at s=2 (par 1) -> init LSB 0 ; buf1 at s=1 (par 0) -> init LSB 1.
__global__ void cvt_x_transpose(const float* __restrict__ in, u16* __restrict__ out,
                                u32* __restrict__ hbuf_u) {
  int gid = blockIdx.x * blockDim.x + threadIdx.x;
  if (gid < 65536) hbuf_u[gid] = ((gid >> 13) & 1) ? 1u : 0u;
  if (gid >= 64 * 512 * 64) return;
  int k8 = gid & 63, t = (gid >> 6) & 511, n = gid >> 15;
  const float* src = in + ((size_t)(n * 512 + t) << 9) + (k8 << 3);
  float4 a = reinterpret_cast<const float4*>(src)[0];
  float4 b = reinterpret_cast<const float4*>(src)[1];
  union { u16 u[8]; uint4 d; } o;
  o.u[0] = f2bf(a.x); o.u[1] = f2bf(a.y); o.u[2] = f2bf(a.z); o.u[3] = f2bf(a.w);
  o.u[4] = f2bf(b.x); o.u[5] = f2bf(b.y); o.u[6] = f2bf(b.z); o.u[7] = f2bf(b.w);
  *reinterpret_cast<uint4*>(out + ((size_t)(t * 64 + n) << 9) + (k8 << 3)) = o.d;
}

// ---------- batch-partitioned LSTM: 4 independent groups of 16 batch rows ----------
// 256 blocks x 256 threads. Block b: group grp=b&3 (rows 16grp..+15), slice sli=b>>2
// (units 16sli..+15 -> 64 gate rows, local row l = gate*16 + ul).
// w_hh slice bf16 in LDS (once); w_ih slice streamed (L2-resident). 4 waves split K.
// h exchange only within the 64-block group: packed-bf16 parity-tagged words.
__global__ void __launch_bounds__(256, 1) lstm_seq(
    const u16* __restrict__ xb,     // [512][64][512] bf16
    const u16* __restrict__ wib,    // [4096][512] bf16
    const float* __restrict__ w_hh, // [4096][1024] f32
    u32* __restrict__ hbuf_u,       // [4 grp][2][16][512] u32
    float* __restrict__ hTf,        // [64][1024] f32
    const float* __restrict__ b_ih, const float* __restrict__ b_hh) {
  __shared__ u16 wh[64][1032];      // 132,096 B; row l = gate*16 + ul
  __shared__ float gp[4][16][68];   // 17,408 B per-wave K-partial gates

  int blk = blockIdx.x, t = threadIdx.x;
  int grp = blk & 3, sli = blk >> 2;
  int u0 = sli << 4;

  // stage w_hh slice from f32 (once): local l -> global row (l>>4)*1024 + u0 + (l&15)
  for (int idx = t; idx < 64 * 128; idx += 256) {
    int l = idx >> 7, c8 = idx & 127;
    int gr = ((l >> 4) << 10) + u0 + (l & 15);
    const float* src = w_hh + ((size_t)gr << 10) + c8 * 8;
    float4 a = reinterpret_cast<const float4*>(src)[0];
    float4 c = reinterpret_cast<const float4*>(src)[1];
    union { u16 us[8]; bf16x8 v; } o;
    o.us[0] = f2bf(a.x); o.us[1] = f2bf(a.y); o.us[2] = f2bf(a.z); o.us[3] = f2bf(a.w);
    o.us[4] = f2bf(c.x); o.us[5] = f2bf(c.y); o.us[6] = f2bf(c.z); o.us[7] = f2bf(c.w);
    *(bf16x8*)(&wh[l][c8 * 8]) = o.v;
  }

  int lane = t & 63, wv = t >> 6;
  int lr = lane & 15, hi = lane >> 4, lk8 = hi << 3;

  // pointwise mapping: thread t -> (prow = t>>4, pul = t&15); c lives here
  int prow = t >> 4, pul = t & 15;
  float bI = b_ih[u0 + pul]        + b_hh[u0 + pul];
  float bF = b_ih[1024 + u0 + pul] + b_hh[1024 + u0 + pul];
  float bG = b_ih[2048 + u0 + pul] + b_hh[2048 + u0 + pul];
  float bO = b_ih[3072 + u0 + pul] + b_hh[3072 + u0 + pul];
  float c_ = 0.f;

  u32* hgrp = hbuf_u + (grp << 14);   // 2 bufs x 8192 words
  __syncthreads();                     // weights staged

  for (int s = 0; s < 512; ++s) {
    f32x4 acc[4] = {};   // 4 gate n-tiles

    // x-GEMM first (independent of h; overlaps other blocks' h production).
    // wave wv handles x K-quarter [128wv, 128wv+128)
    {
      const u16* xb_ = xb + ((size_t)s << 15) + (size_t)(((grp << 4) + lr) << 9) + (wv << 7) + lk8;
      const u16* wb_ = wib + ((size_t)(u0 + lr) << 9) + (wv << 7) + lk8;
#pragma unroll
      for (int ks = 0; ks < 4; ++ks) {
        bf16x8 a = *(const bf16x8*)(xb_ + ks * 32);
#pragma unroll
        for (int nt = 0; nt < 4; ++nt) {
          bf16x8 bfr = *(const bf16x8*)(wb_ + ((size_t)nt << 19) + ks * 32);
          acc[nt] = __builtin_amdgcn_mfma_f32_16x16x32_bf16(a, bfr, acc[nt], 0, 0, 0);
        }
      }
    }

    if (s > 0) {
      // poll-load h(s) K-quarter [256wv, 256wv+256): lane (lr,hi) -> row lr,
      // words 128wv + 4hi + 16ks + [0,4)  == its A-frags exactly
      const u32* hb4 = hgrp + ((s & 1) << 13) + (lr << 9) + (wv << 7) + (hi << 2);
      u32 par = (u32)((s >> 1) & 1);
      u32x4 ha[8];
      int tries = 0;
      while (true) {
#define LDH(OFF) asm volatile("global_load_dwordx4 %0, %1, off offset:" #OFF " sc0 sc1" \
                              : "=v"(ha[OFF / 64]) : "v"(hb4) : "memory");
        LDH(0) LDH(64) LDH(128) LDH(192) LDH(256) LDH(320) LDH(384) LDH(448)
#undef LDH
        asm volatile("s_waitcnt vmcnt(0)" ::: "memory");
        __builtin_amdgcn_sched_barrier(0);          // rule #18
        u32 ok;
        if (par) {
          u32 r = 0xFFFFFFFFu;
#pragma unroll
          for (int i2 = 0; i2 < 8; ++i2)
            r &= (ha[i2][0] & ha[i2][1]) & (ha[i2][2] & ha[i2][3]);
          ok = r & 1u;
        } else {
          u32 r = 0u;
#pragma unroll
          for (int i2 = 0; i2 < 8; ++i2)
            r |= (ha[i2][0] | ha[i2][1]) | (ha[i2][2] | ha[i2][3]);
          ok = (~r) & 1u;
        }
        if (__all((int)ok)) break;
        if (++tries > (1 << 20)) break;             // fail loud, never hang
        __builtin_amdgcn_s_sleep(1);
      }
      __builtin_amdgcn_sched_barrier(0);
      // h-GEMM over this wave's K-quarter (captured regs ARE the A-frags)
#pragma unroll
      for (int ks = 0; ks < 8; ++ks) {
        union { u32x4 uu; bf16x8 v; } af; af.uu = ha[ks];
#pragma unroll
        for (int nt = 0; nt < 4; ++nt) {
          bf16x8 bfr = *(const bf16x8*)(&wh[(nt << 4) + lr][(wv << 8) + ks * 32 + lk8]);
          acc[nt] = __builtin_amdgcn_mfma_f32_16x16x32_bf16(af.v, bfr, acc[nt], 0, 0, 0);
        }
      }
    }

    // per-wave K-partials -> LDS
#pragma unroll
    for (int nt = 0; nt < 4; ++nt)
#pragma unroll
      for (int q = 0; q < 4; ++q)
        gp[wv][(hi << 2) + q][(nt << 4) + lr] = acc[nt][q];
    __syncthreads();

    // pointwise: reduce 4 wave-partials, cell update, emit h
    float g0 = gp[0][prow][pul]      + gp[1][prow][pul]      + gp[2][prow][pul]      + gp[3][prow][pul]      + bI;
    float g1 = gp[0][prow][16 + pul] + gp[1][prow][16 + pul] + gp[2][prow][16 + pul] + gp[3][prow][16 + pul] + bF;
    float g2 = gp[0][prow][32 + pul] + gp[1][prow][32 + pul] + gp[2][prow][32 + pul] + gp[3][prow][32 + pul] + bG;
    float g3 = gp[0][prow][48 + pul] + gp[1][prow][48 + pul] + gp[2][prow][48 + pul] + gp[3][prow][48 + pul] + bO;
    float ii = sigm(g0), ff = sigm(g1), tg = tanh_fast(g2), oo = sigm(g3);
    float cn = ff * c_ + ii * tg;
    c_ = cn;
    float hv = oo * tanh_fast(cn);
    if (s == 511) {
      hTf[((size_t)((grp << 4) + prow) << 10) + u0 + pul] = hv;  // plain; kernel-end flush
    } else {
      u32 hb = (u32)f2bf(hv);
      u32 pn = (u32)__shfl_xor((int)hb, 1, 64);     // partner unit (pul^1), same wave
      if (!(pul & 1)) {
        u32 par1 = (u32)(((s + 1) >> 1) & 1);
        u32 wdat = ((hb & ~1u) | par1) | (pn << 16);
        u32* dst = hgrp + (((s + 1) & 1) << 13) + (prow << 9) + (sli << 3) + (pul >> 1);
        asm volatile("global_store_dword %0, %1, off sc0 sc1" :: "v"(dst), "v"(wdat) : "memory");
      }
    }
    __syncthreads();   // protect gp before next step's rewrite
  }
}

// ---------- FC head: block n computes out[n] ----------
__global__ void fc_head(const float* __restrict__ hTf, const float* __restrict__ fc_w,
                        const float* __restrict__ fc_b, float* __restrict__ out) {
  __shared__ float red[4];
  int n = blockIdx.x, t = threadIdx.x;
  float4 hv = *(const float4*)(hTf + (n << 10) + t * 4);
  float4 wv = *(const float4*)(fc_w + t * 4);
  float s = hv.x * wv.x + hv.y * wv.y + hv.z * wv.z + hv.w * wv.w;
#pragma unroll
  for (int o = 32; o; o >>= 1) s += __shfl_down(s, o, 64);
  if ((t & 63) == 0) red[t >> 6] = s;
  __syncthreads();
  if (t == 0) out[n] = sigm(red[0] + red[1] + red[2] + red[3] + fc_b[0]);
}

// ---------- launch ----------
extern "C" void kernel_launch(void* const* d_in, const int* in_sizes, int n_in,
                              void* d_out, int out_size, void* d_ws, size_t ws_size,
                              hipStream_t stream) {
  const float* x    = (const float*)d_in[0];
  const float* w_ih = (const float*)d_in[1];
  const float* w_hh = (const float*)d_in[2];
  const float* b_ih = (const float*)d_in[3];
  const float* b_hh = (const float*)d_in[4];
  const float* fc_w = (const float*)d_in[5];
  const float* fc_b = (const float*)d_in[6];
  float* out = (float*)d_out;

  char* ws = (char*)d_ws;
  u16*   xb     = (u16*)(ws);                  // 33,554,432 B
  u16*   wib    = (u16*)(ws + 33554432);       //  4,194,304 B
  u32*   hbuf_u = (u32*)(ws + 37748736);       //    262,144 B  [4][2][16][512] u32
  float* hTf    = (float*)(ws + 38010880);     //    262,144 B

  cvt_x_transpose<<<8192, 256, 0, stream>>>(x, xb, hbuf_u);
  cvt_f32_bf16_v4<<<512, 256, 0, stream>>>(w_ih, wib, 2097152 / 4);
  lstm_seq<<<256, 256, 0, stream>>>(xb, wib, w_hh, hbuf_u, hTf, b_ih, b_hh);
  fc_head<<<64, 256, 0, stream>>>(hTf, fc_w, fc_b, out);
}